// Round 1
// baseline (9933.513 us; speedup 1.0000x reference)
//
#include <hip/hip_runtime.h>

// SimpleRNN baseline (round 0): correctness-first, fp32 vector math.
// Structure: 512 per-step kernels (graph nodes) + 2 FC kernels + softmax head.
// h ping-pongs in ws; kernel boundaries give device-wide coherence (no
// intra-kernel cross-block sync needed). Later rounds: persistent bf16 MFMA
// column-split RNN kernel.

constexpr int Bn = 256;   // batch
constexpr int Tn = 512;   // seq len
constexpr int En = 100;   // embed dim
constexpr int Un = 512;   // rnn units
constexpr int D1n = 1024;
constexpr int D2n = 1024;
constexpr int Cn = 10;

// ---------------------------------------------------------------------------
// One RNN step: h_out[b,u] = mask(b,t) ? relu(b_rnn[u] + emb[tok]@Wx + h_in@Wh)
//                                      : h_in[b,u]
// Grid: (Un/32, Bn/16) = (16,16) blocks, 256 threads.
// Each block: 16 rows x 32 cols of h_out; h rows staged in LDS.
// ---------------------------------------------------------------------------
__global__ __launch_bounds__(256) void rnn_step(
    const int* __restrict__ tokens, const float* __restrict__ emb,
    const float* __restrict__ Wx, const float* __restrict__ Wh,
    const float* __restrict__ b_rnn,
    const float* __restrict__ h_in, float* __restrict__ h_out, int t)
{
    __shared__ float h_lds[16][Un];   // 32 KB
    __shared__ float x_lds[16][En];   // 6.4 KB (row stride 400B, 16B-aligned)
    __shared__ int   tok_lds[16];

    const int tid = threadIdx.x;
    const int r0  = blockIdx.y * 16;
    const int c0  = blockIdx.x * 32;

    if (tid < 16) tok_lds[tid] = tokens[(r0 + tid) * Tn + t];
    for (int i = tid; i < 16 * Un; i += 256) {
        int r = i >> 9, c = i & (Un - 1);
        h_lds[r][c] = h_in[(r0 + r) * Un + c];
    }
    for (int i = tid; i < 16 * En; i += 256) {
        int r = i / En, c = i - r * En;
        x_lds[r][c] = emb[tokens[(r0 + r) * Tn + t] * En + c];
    }
    __syncthreads();

    const int col = c0 + (tid & 31);
    const int rb  = (tid >> 5) * 2;       // 2 rows per thread

    float acc0 = b_rnn[col];
    float acc1 = acc0;

    const float4* h0v = (const float4*)(&h_lds[rb][0]);
    const float4* h1v = (const float4*)(&h_lds[rb + 1][0]);
    for (int k4 = 0; k4 < Un / 4; ++k4) {
        float4 ha = h0v[k4];
        float4 hb = h1v[k4];
        int k = k4 * 4;
        float w0 = Wh[(k + 0) * Un + col];
        float w1 = Wh[(k + 1) * Un + col];
        float w2 = Wh[(k + 2) * Un + col];
        float w3 = Wh[(k + 3) * Un + col];
        acc0 += ha.x * w0; acc0 += ha.y * w1; acc0 += ha.z * w2; acc0 += ha.w * w3;
        acc1 += hb.x * w0; acc1 += hb.y * w1; acc1 += hb.z * w2; acc1 += hb.w * w3;
    }

    const float4* x0v = (const float4*)(&x_lds[rb][0]);
    const float4* x1v = (const float4*)(&x_lds[rb + 1][0]);
    for (int k4 = 0; k4 < En / 4; ++k4) {   // En = 100 = 25 * 4
        float4 xa = x0v[k4];
        float4 xb = x1v[k4];
        int k = k4 * 4;
        float w0 = Wx[(k + 0) * Un + col];
        float w1 = Wx[(k + 1) * Un + col];
        float w2 = Wx[(k + 2) * Un + col];
        float w3 = Wx[(k + 3) * Un + col];
        acc0 += xa.x * w0; acc0 += xa.y * w1; acc0 += xa.z * w2; acc0 += xa.w * w3;
        acc1 += xb.x * w0; acc1 += xb.y * w1; acc1 += xb.z * w2; acc1 += xb.w * w3;
    }

    {
        int row = r0 + rb;
        bool m0 = tok_lds[rb] != 0;
        bool m1 = tok_lds[rb + 1] != 0;
        h_out[row * Un + col]       = m0 ? fmaxf(acc0, 0.f) : h_lds[rb][col];
        h_out[(row + 1) * Un + col] = m1 ? fmaxf(acc1, 0.f) : h_lds[rb + 1][col];
    }
}

// ---------------------------------------------------------------------------
// FC layer: out[B,N] = (relu?)(in[B,K] @ W[K,N] + b)
// Grid: (N/32, B/16), 256 threads. K-template so LDS is static.
// ---------------------------------------------------------------------------
template <int K, bool RELU>
__global__ __launch_bounds__(256) void fc(
    const float* __restrict__ in, const float* __restrict__ W,
    const float* __restrict__ b, float* __restrict__ out, int N)
{
    __shared__ float in_lds[16][K];   // K=512 -> 32KB, K=1024 -> 64KB
    const int tid = threadIdx.x;
    const int r0  = blockIdx.y * 16;
    const int c0  = blockIdx.x * 32;

    for (int i = tid; i < 16 * K; i += 256) {
        int r = i / K, c = i - r * K;
        in_lds[r][c] = in[(r0 + r) * K + c];
    }
    __syncthreads();

    const int col = c0 + (tid & 31);
    const int rb  = (tid >> 5) * 2;

    float acc0 = b[col];
    float acc1 = acc0;
    const float4* i0v = (const float4*)(&in_lds[rb][0]);
    const float4* i1v = (const float4*)(&in_lds[rb + 1][0]);
    for (int k4 = 0; k4 < K / 4; ++k4) {
        float4 a = i0v[k4];
        float4 c = i1v[k4];
        int k = k4 * 4;
        float w0 = W[(k + 0) * N + col];
        float w1 = W[(k + 1) * N + col];
        float w2 = W[(k + 2) * N + col];
        float w3 = W[(k + 3) * N + col];
        acc0 += a.x * w0; acc0 += a.y * w1; acc0 += a.z * w2; acc0 += a.w * w3;
        acc1 += c.x * w0; acc1 += c.y * w1; acc1 += c.z * w2; acc1 += c.w * w3;
    }
    if (RELU) { acc0 = fmaxf(acc0, 0.f); acc1 = fmaxf(acc1, 0.f); }
    out[(r0 + rb) * N + col]     = acc0;
    out[(r0 + rb + 1) * N + col] = acc1;
}

// ---------------------------------------------------------------------------
// Head: logits = h2[B,D2] @ Wo[D2,C] + bo; out = softmax(logits). 1 wave/row.
// ---------------------------------------------------------------------------
__global__ __launch_bounds__(64) void head_softmax(
    const float* __restrict__ h2, const float* __restrict__ Wo,
    const float* __restrict__ bo, float* __restrict__ out)
{
    const int b    = blockIdx.x;
    const int lane = threadIdx.x;

    float acc[Cn];
#pragma unroll
    for (int c = 0; c < Cn; ++c) acc[c] = 0.f;

    for (int k = lane; k < D2n; k += 64) {
        float hv = h2[b * D2n + k];
#pragma unroll
        for (int c = 0; c < Cn; ++c) acc[c] += hv * Wo[k * Cn + c];
    }
#pragma unroll
    for (int c = 0; c < Cn; ++c) {
#pragma unroll
        for (int off = 32; off > 0; off >>= 1)
            acc[c] += __shfl_down(acc[c], off);
    }
    if (lane == 0) {
        float l[Cn], mx = -1e30f;
#pragma unroll
        for (int c = 0; c < Cn; ++c) { l[c] = acc[c] + bo[c]; mx = fmaxf(mx, l[c]); }
        float s = 0.f;
#pragma unroll
        for (int c = 0; c < Cn; ++c) { l[c] = __expf(l[c] - mx); s += l[c]; }
        float inv = 1.f / s;
#pragma unroll
        for (int c = 0; c < Cn; ++c) out[b * Cn + c] = l[c] * inv;
    }
}

extern "C" void kernel_launch(void* const* d_in, const int* in_sizes, int n_in,
                              void* d_out, int out_size, void* d_ws, size_t ws_size,
                              hipStream_t stream)
{
    const int*   tokens = (const int*)d_in[0];
    const float* emb    = (const float*)d_in[1];
    const float* Wx     = (const float*)d_in[2];
    const float* Wh     = (const float*)d_in[3];
    const float* b_rnn  = (const float*)d_in[4];
    const float* W1     = (const float*)d_in[5];
    const float* b1     = (const float*)d_in[6];
    const float* W2     = (const float*)d_in[7];
    const float* b2     = (const float*)d_in[8];
    const float* Wo     = (const float*)d_in[9];
    const float* bo     = (const float*)d_in[10];
    float* out = (float*)d_out;

    float* ws     = (float*)d_ws;
    float* h_ping = ws;                      // Bn*Un
    float* h_pong = ws + Bn * Un;            // Bn*Un
    float* h1     = ws + 2 * Bn * Un;        // Bn*D1n
    float* h2     = h1 + Bn * D1n;           // Bn*D2n
    // total ws use: 3 MB

    hipMemsetAsync(h_ping, 0, Bn * Un * sizeof(float), stream);

    dim3 bs(256);
    dim3 gs_rnn(Un / 32, Bn / 16);
    const float* hin = h_ping;
    float* hout = h_pong;
    for (int t = 0; t < Tn; ++t) {
        rnn_step<<<gs_rnn, bs, 0, stream>>>(tokens, emb, Wx, Wh, b_rnn, hin, hout, t);
        const float* tmp = hout;
        hout = (float*)hin;
        hin = tmp;
    }
    // T is even -> final h is back in h_ping (pointed to by hin)

    fc<Un, true><<<dim3(D1n / 32, Bn / 16), bs, 0, stream>>>(hin, W1, b1, h1, D1n);
    fc<D1n, true><<<dim3(D2n / 32, Bn / 16), bs, 0, stream>>>(h1, W2, b2, h2, D2n);
    head_softmax<<<Bn, 64, 0, stream>>>(h2, Wo, bo, out);
}

// Round 2
// 2464.454 us; speedup vs baseline: 4.0307x; 4.0307x over previous
//
#include <hip/hip_runtime.h>

// Round 2: persistent batch-parallel RNN. 16 blocks x 512 threads; each block
// owns 16 batch rows and runs all 512 timesteps internally (rows are
// independent across the recurrence -> no cross-block sync at all).
// h in LDS (bf16, double-buffered, XOR-swizzled); Wh/Wx pre-packed into
// MFMA B-fragment order so per-step weight streams are coalesced dwordx4.

typedef __attribute__((ext_vector_type(8))) short bf16x8_t;
typedef __attribute__((ext_vector_type(4))) float f32x4_t;

constexpr int Bn = 256;   // batch
constexpr int Tn = 512;   // seq len
constexpr int En = 100;   // embed dim
constexpr int Un = 512;   // rnn units
constexpr int D1n = 1024;
constexpr int D2n = 1024;
constexpr int Cn = 10;
constexpr int Kx = 128;   // padded embed K for MFMA (100 -> 128)

__device__ __forceinline__ ushort f2bf(float x) {
    unsigned u = __float_as_uint(x);
    unsigned r = (u + 0x7FFFu + ((u >> 16) & 1u)) >> 16;   // RNE
    return (ushort)r;
}

// ---------------------------------------------------------------------------
// Pack Wh [512][512] f32 -> bf16 B-fragment tile order.
// Fragment for tile (nt, kt): lane l, reg j holds Wh[kt*32+(l>>4)*8+j][nt*16+(l&15)].
// Packed element index e = ((nt*16 + kt)*64 + l)*8 + j.
// ---------------------------------------------------------------------------
__global__ __launch_bounds__(256) void pack_wh(const float* __restrict__ Wh,
                                               ushort* __restrict__ WhP) {
    int e = blockIdx.x * 256 + threadIdx.x;           // < 262144
    int j = e & 7, l = (e >> 3) & 63, kt = (e >> 9) & 15, nt = e >> 13;
    int k = kt * 32 + (l >> 4) * 8 + j;
    int c = nt * 16 + (l & 15);
    WhP[e] = f2bf(Wh[k * Un + c]);
}

// Wx [100][512] -> padded [128][512], same fragment order (4 K-steps).
__global__ __launch_bounds__(256) void pack_wx(const float* __restrict__ Wx,
                                               ushort* __restrict__ WxP) {
    int e = blockIdx.x * 256 + threadIdx.x;           // < 65536
    int j = e & 7, l = (e >> 3) & 63, kt = (e >> 9) & 3, nt = e >> 11;
    int k = kt * 32 + (l >> 4) * 8 + j;
    int c = nt * 16 + (l & 15);
    WxP[e] = (k < En) ? f2bf(Wx[k * Un + c]) : (ushort)0;
}

// ---------------------------------------------------------------------------
// Persistent RNN kernel. Grid = 16 blocks, 512 threads (8 waves).
// Wave w owns output cols [w*64, w*64+64) = 4 N-tiles of 16.
// LDS (ushort units): H0 @0 (8192), H1 @8192, X0 @16384 (2048), X1 @18432,
//                     TOK @20480 (8192).  Total 28672 ushorts = 56 KB.
// ---------------------------------------------------------------------------
__global__ __launch_bounds__(512) void rnn_persist(
    const int* __restrict__ tokens, const float* __restrict__ emb,
    const float* __restrict__ b_rnn,
    const ushort* __restrict__ WhP, const ushort* __restrict__ WxP,
    float* __restrict__ h_final)
{
    __shared__ ushort sh[28672];

    const int tid  = threadIdx.x;
    const int lane = tid & 63;
    const int wv   = tid >> 6;          // 0..7
    const int r0   = blockIdx.x * 16;

    const int r16 = lane & 15;          // A row / D col within tile
    const int q   = lane >> 4;          // 0..3
    const int rb  = q * 4;              // D row base
    const int aswz = (r16 & 7) << 4;    // A-read swizzle

    // ---- stage tokens (16 rows x 512 t, coalesced: 8192 contiguous ints) --
    for (int f = tid; f < 16 * Tn; f += 512)
        sh[20480 + f] = (ushort)tokens[r0 * Tn + f];
    // ---- zero h ping and both x buffers ----
    for (int f = tid; f < 8192; f += 512) sh[f] = 0;
    for (int f = tid; f < 4096; f += 512) sh[16384 + f] = 0;
    __syncthreads();

    // embedding-prefetch assignment (400 active threads: 16 rows x 25 float4)
    const int prow = tid / 25;
    const int pc4  = tid - prow * 25;
    const bool is_pref = (tid < 400);

    // initial gather for t = 0 into X0
    if (is_pref) {
        int tk = (int)sh[20480 + prow * Tn + 0];
        float4 v = *(const float4*)(emb + tk * En + pc4 * 4);
        unsigned lo = (unsigned)f2bf(v.x) | ((unsigned)f2bf(v.y) << 16);
        unsigned hi = (unsigned)f2bf(v.z) | ((unsigned)f2bf(v.w) << 16);
        char* xb = (char*)(sh + 16384);
        *(uint2*)(xb + ((prow * 256 + pc4 * 8) ^ ((prow & 7) << 4))) =
            make_uint2(lo, hi);
    }
    __syncthreads();

    // per-lane bias for the 4 owned N-tiles
    float bias_r[4];
#pragma unroll
    for (int p = 0; p < 4; ++p)
        bias_r[p] = b_rnn[(wv * 4 + p) * 16 + r16];

    float hprev[4][4];
#pragma unroll
    for (int p = 0; p < 4; ++p)
#pragma unroll
        for (int j = 0; j < 4; ++j) hprev[p][j] = 0.f;

    int cur = 0;
    for (int t = 0; t < Tn; ++t) {
        const char* hcB = (const char*)(sh + (cur ? 8192 : 0));
        char*       hnB = (char*)(sh + (cur ? 0 : 8192));
        const char* xcB = (const char*)(sh + 16384 + (cur ? 2048 : 0));
        char*       xnB = (char*)(sh + 16384 + (cur ? 0 : 2048));

        // prefetch next-step embedding rows (in flight during MFMA)
        float4 pref;
        const bool do_pref = is_pref && (t + 1 < Tn);
        if (do_pref) {
            int tk = (int)sh[20480 + prow * Tn + (t + 1)];
            pref = *(const float4*)(emb + tk * En + pc4 * 4);
        }

        f32x4_t acc[4];
#pragma unroll
        for (int p = 0; p < 4; ++p) acc[p] = (f32x4_t){0.f, 0.f, 0.f, 0.f};

        // h @ Wh : K = 512 (16 steps of 32)
#pragma unroll 4
        for (int kt = 0; kt < 16; ++kt) {
            bf16x8_t a = *(const bf16x8_t*)(hcB +
                ((r16 * 1024 + kt * 64 + q * 16) ^ aswz));
#pragma unroll
            for (int p = 0; p < 4; ++p) {
                int nt = wv * 4 + p;
                bf16x8_t b = *(const bf16x8_t*)(WhP + ((nt * 16 + kt) * 512 + lane * 8));
                acc[p] = __builtin_amdgcn_mfma_f32_16x16x32_bf16(a, b, acc[p], 0, 0, 0);
            }
        }
        // x @ Wx : K = 128 (4 steps of 32; cols 100..127 are zero)
#pragma unroll
        for (int kt = 0; kt < 4; ++kt) {
            bf16x8_t a = *(const bf16x8_t*)(xcB +
                ((r16 * 256 + kt * 64 + q * 16) ^ aswz));
#pragma unroll
            for (int p = 0; p < 4; ++p) {
                int nt = wv * 4 + p;
                bf16x8_t b = *(const bf16x8_t*)(WxP + ((nt * 4 + kt) * 512 + lane * 8));
                acc[p] = __builtin_amdgcn_mfma_f32_16x16x32_bf16(a, b, acc[p], 0, 0, 0);
            }
        }

        // epilogue: bias + relu + mask-carry, write h_next (bf16, swizzled)
        bool mk[4];
#pragma unroll
        for (int j = 0; j < 4; ++j)
            mk[j] = sh[20480 + (rb + j) * Tn + t] != 0;
#pragma unroll
        for (int p = 0; p < 4; ++p) {
            int n = (wv * 4 + p) * 16 + r16;
#pragma unroll
            for (int j = 0; j < 4; ++j) {
                float v = acc[p][j] + bias_r[p];
                v = fmaxf(v, 0.f);
                v = mk[j] ? v : hprev[p][j];
                hprev[p][j] = v;
                int r = rb + j;
                *(ushort*)(hnB + ((r * 1024 + n * 2) ^ ((r & 7) << 4))) = f2bf(v);
            }
        }
        // write prefetched x for t+1
        if (do_pref) {
            unsigned lo = (unsigned)f2bf(pref.x) | ((unsigned)f2bf(pref.y) << 16);
            unsigned hi = (unsigned)f2bf(pref.z) | ((unsigned)f2bf(pref.w) << 16);
            *(uint2*)(xnB + ((prow * 256 + pc4 * 8) ^ ((prow & 7) << 4))) =
                make_uint2(lo, hi);
        }
        __syncthreads();
        cur ^= 1;
    }

    // final h -> global fp32 (bf16 bits << 16)
    const char* hfB = (const char*)(sh + (cur ? 8192 : 0));
    for (int f = tid; f < 16 * Un; f += 512) {
        int r = f >> 9, c = f & 511;
        unsigned bits = *(const ushort*)(hfB + ((r * 1024 + c * 2) ^ ((r & 7) << 4)));
        h_final[r0 * Un + f] = __uint_as_float(bits << 16);
    }
}

// ---------------------------------------------------------------------------
// MLP head (unchanged from round 0 — verified correct, small share of time)
// ---------------------------------------------------------------------------
template <int K, bool RELU>
__global__ __launch_bounds__(256) void fc(
    const float* __restrict__ in, const float* __restrict__ W,
    const float* __restrict__ b, float* __restrict__ out, int N)
{
    __shared__ float in_lds[16][K];
    const int tid = threadIdx.x;
    const int r0  = blockIdx.y * 16;
    const int c0  = blockIdx.x * 32;

    for (int i = tid; i < 16 * K; i += 256) {
        int r = i / K, c = i - r * K;
        in_lds[r][c] = in[(r0 + r) * K + c];
    }
    __syncthreads();

    const int col = c0 + (tid & 31);
    const int rb  = (tid >> 5) * 2;

    float acc0 = b[col];
    float acc1 = acc0;
    const float4* i0v = (const float4*)(&in_lds[rb][0]);
    const float4* i1v = (const float4*)(&in_lds[rb + 1][0]);
    for (int k4 = 0; k4 < K / 4; ++k4) {
        float4 a = i0v[k4];
        float4 c = i1v[k4];
        int k = k4 * 4;
        float w0 = W[(k + 0) * N + col];
        float w1 = W[(k + 1) * N + col];
        float w2 = W[(k + 2) * N + col];
        float w3 = W[(k + 3) * N + col];
        acc0 += a.x * w0; acc0 += a.y * w1; acc0 += a.z * w2; acc0 += a.w * w3;
        acc1 += c.x * w0; acc1 += c.y * w1; acc1 += c.z * w2; acc1 += c.w * w3;
    }
    if (RELU) { acc0 = fmaxf(acc0, 0.f); acc1 = fmaxf(acc1, 0.f); }
    out[(r0 + rb) * N + col]     = acc0;
    out[(r0 + rb + 1) * N + col] = acc1;
}

__global__ __launch_bounds__(64) void head_softmax(
    const float* __restrict__ h2, const float* __restrict__ Wo,
    const float* __restrict__ bo, float* __restrict__ out)
{
    const int b    = blockIdx.x;
    const int lane = threadIdx.x;

    float acc[Cn];
#pragma unroll
    for (int c = 0; c < Cn; ++c) acc[c] = 0.f;

    for (int k = lane; k < D2n; k += 64) {
        float hv = h2[b * D2n + k];
#pragma unroll
        for (int c = 0; c < Cn; ++c) acc[c] += hv * Wo[k * Cn + c];
    }
#pragma unroll
    for (int c = 0; c < Cn; ++c) {
#pragma unroll
        for (int off = 32; off > 0; off >>= 1)
            acc[c] += __shfl_down(acc[c], off);
    }
    if (lane == 0) {
        float l[Cn], mx = -1e30f;
#pragma unroll
        for (int c = 0; c < Cn; ++c) { l[c] = acc[c] + bo[c]; mx = fmaxf(mx, l[c]); }
        float s = 0.f;
#pragma unroll
        for (int c = 0; c < Cn; ++c) { l[c] = __expf(l[c] - mx); s += l[c]; }
        float inv = 1.f / s;
#pragma unroll
        for (int c = 0; c < Cn; ++c) out[b * Cn + c] = l[c] * inv;
    }
}

extern "C" void kernel_launch(void* const* d_in, const int* in_sizes, int n_in,
                              void* d_out, int out_size, void* d_ws, size_t ws_size,
                              hipStream_t stream)
{
    const int*   tokens = (const int*)d_in[0];
    const float* emb    = (const float*)d_in[1];
    const float* Wx     = (const float*)d_in[2];
    const float* Wh     = (const float*)d_in[3];
    const float* b_rnn  = (const float*)d_in[4];
    const float* W1     = (const float*)d_in[5];
    const float* b1     = (const float*)d_in[6];
    const float* W2     = (const float*)d_in[7];
    const float* b2     = (const float*)d_in[8];
    const float* Wo     = (const float*)d_in[9];
    const float* bo     = (const float*)d_in[10];
    float* out = (float*)d_out;

    char* ws = (char*)d_ws;
    ushort* WhP    = (ushort*)ws;                       // 512 KB
    ushort* WxP    = (ushort*)(ws + (512 << 10));       // 128 KB
    float*  h_last = (float*)(ws + (640 << 10));        // 512 KB
    float*  h1     = (float*)(ws + (1152 << 10));       // 1 MB
    float*  h2     = (float*)(ws + (2176 << 10));       // 1 MB  (total 3.2 MB)

    pack_wh<<<Un * Un / 256, 256, 0, stream>>>(Wh, WhP);
    pack_wx<<<Kx * Un / 256, 256, 0, stream>>>(Wx, WxP);

    rnn_persist<<<Bn / 16, 512, 0, stream>>>(tokens, emb, b_rnn, WhP, WxP, h_last);

    dim3 bs(256);
    fc<Un, true><<<dim3(D1n / 32, Bn / 16), bs, 0, stream>>>(h_last, W1, b1, h1, D1n);
    fc<D1n, true><<<dim3(D2n / 32, Bn / 16), bs, 0, stream>>>(h1, W2, b2, h2, D2n);
    head_softmax<<<Bn, 64, 0, stream>>>(h2, Wo, bo, out);
}

// Round 3
// 1013.383 us; speedup vs baseline: 9.8023x; 2.4319x over previous
//
#include <hip/hip_runtime.h>

// Round 3: fp8 weight-resident persistent RNN.
// 16 blocks x 512 threads (8 waves, 1 block/CU, 2 waves/SIMD).
// Each wave holds its Wh column-slice (512x64) + Wx slice (128x64) as e4m3
// B-fragments IN REGISTERS (128+32 VGPR) -> zero per-step weight traffic.
// h/x quantized to e4m3 (scale 2^8) in LDS; acc descaled by 2^-16.
// hprev carry stays exact fp32 in registers.

typedef __attribute__((ext_vector_type(4))) float f32x4_t;

constexpr int Bn = 256, Tn = 512, En = 100, Un = 512;
constexpr int D1n = 1024, D2n = 1024, Cn = 10;
constexpr float QS  = 256.f;               // input/weight quant scale 2^8
constexpr float INV = 1.52587890625e-05f;  // 2^-16

// ---- fp8 e4m3fn conversion helpers ----------------------------------------
__device__ __forceinline__ unsigned f2e4m3_sw(float x) {
    unsigned u = __float_as_uint(x);
    unsigned sgn = (u >> 24) & 0x80;
    float a = __uint_as_float(u & 0x7FFFFFFF);
    if (a >= 448.f) return sgn | 0x7E;
    if (a < 0.015625f) {                   // subnormal: step 2^-9
        unsigned q = (unsigned)__float2int_rn(a * 512.f);
        return sgn | q;                    // q==8 -> 0x08 == 2^-6 normal, ok
    }
    int e = (int)((u >> 23) & 0xFF) - 127;
    unsigned m = u & 0x7FFFFF;
    unsigned mant = m >> 20, rem = m & 0xFFFFF;
    if (rem > 0x80000 || (rem == 0x80000 && (mant & 1))) {
        if (++mant == 8) { mant = 0; ++e; }
    }
    if (e > 8) return sgn | 0x7E;
    return sgn | ((unsigned)(e + 7) << 3) | mant;
}

__device__ __forceinline__ unsigned cvt1(float x) {
#if __has_builtin(__builtin_amdgcn_cvt_pk_fp8_f32)
    return (unsigned)__builtin_amdgcn_cvt_pk_fp8_f32(x, x, 0, false) & 0xFFu;
#else
    return f2e4m3_sw(x);
#endif
}

__device__ __forceinline__ unsigned pk4(float a, float b, float c, float d) {
#if __has_builtin(__builtin_amdgcn_cvt_pk_fp8_f32)
    int r = __builtin_amdgcn_cvt_pk_fp8_f32(a, b, 0, false);
    r = __builtin_amdgcn_cvt_pk_fp8_f32(c, d, r, true);
    return (unsigned)r;
#else
    return f2e4m3_sw(a) | (f2e4m3_sw(b) << 8) | (f2e4m3_sw(c) << 16) |
           (f2e4m3_sw(d) << 24);
#endif
}

// ---------------------------------------------------------------------------
// Pack Wh [512][512] f32 -> fp8 B-fragment order (scaled by QS).
// frag (nt,kt): lane l, byte j holds Wh[kt*32+(l>>4)*8+j][nt*16+(l&15)].
// ---------------------------------------------------------------------------
__global__ __launch_bounds__(256) void pack_wh8(const float* __restrict__ Wh,
                                                unsigned char* __restrict__ P) {
    int e = blockIdx.x * 256 + threadIdx.x;          // < 262144
    int j = e & 7, l = (e >> 3) & 63, kt = (e >> 9) & 15, nt = e >> 13;
    int k = kt * 32 + (l >> 4) * 8 + j;
    int c = nt * 16 + (l & 15);
    P[e] = (unsigned char)cvt1(Wh[k * Un + c] * QS);
}

__global__ __launch_bounds__(256) void pack_wx8(const float* __restrict__ Wx,
                                                unsigned char* __restrict__ P) {
    int e = blockIdx.x * 256 + threadIdx.x;          // < 65536
    int j = e & 7, l = (e >> 3) & 63, kt = (e >> 9) & 3, nt = e >> 11;
    int k = kt * 32 + (l >> 4) * 8 + j;
    int c = nt * 16 + (l & 15);
    P[e] = (k < En) ? (unsigned char)cvt1(Wx[k * Un + c] * QS) : 0;
}

// ---------------------------------------------------------------------------
// Persistent RNN. LDS bytes: H0@0(8192) H1@8192 X0@16384(2048) X1@18432
//                            TOK(ushort)@20480(16384) -> 36 KB total.
// Swizzle: byte_addr ^= (row&15)<<3  (conflict-free b64 A-reads).
// ---------------------------------------------------------------------------
__global__ __launch_bounds__(512, 2) void rnn_persist8(
    const int* __restrict__ tokens, const float* __restrict__ emb,
    const float* __restrict__ b_rnn,
    const long* __restrict__ WhP8, const long* __restrict__ WxP8,
    float* __restrict__ h_final)
{
    __shared__ char sh[36864];
    char* H0 = sh;            char* H1 = sh + 8192;
    char* X0 = sh + 16384;    char* X1 = sh + 18432;
    ushort* TOK = (ushort*)(sh + 20480);

    const int tid  = threadIdx.x;
    const int lane = tid & 63;
    const int wv   = tid >> 6;
    const int r0   = blockIdx.x * 16;

    const int r16  = lane & 15;
    const int q    = lane >> 4;
    const int rb   = q * 4;
    const int aswz = r16 << 3;

    for (int f = tid; f < 16 * Tn; f += 512)
        TOK[f] = (ushort)tokens[r0 * Tn + f];
    {   // zero H0 and X0+X1
        int* z = (int*)sh;
        for (int f = tid; f < 2048; f += 512) z[f] = 0;
        int* zx = (int*)(sh + 16384);
        for (int f = tid; f < 1024; f += 512) zx[f] = 0;
    }
    __syncthreads();

    // ---- weight fragments -> registers (fully static indexing) ----
    long whf[16][4], wxf[4][4];
#pragma unroll
    for (int kt = 0; kt < 16; ++kt)
#pragma unroll
        for (int p = 0; p < 4; ++p)
            whf[kt][p] = WhP8[((wv * 4 + p) * 16 + kt) * 64 + lane];
#pragma unroll
    for (int kt = 0; kt < 4; ++kt)
#pragma unroll
        for (int p = 0; p < 4; ++p)
            wxf[kt][p] = WxP8[((wv * 4 + p) * 4 + kt) * 64 + lane];

    float bias_r[4];
#pragma unroll
    for (int p = 0; p < 4; ++p)
        bias_r[p] = b_rnn[(wv * 4 + p) * 16 + r16];

    // embedding prefetch mapping: 400 threads = 16 rows x 25 float4
    const int prow = tid / 25;
    const int pc4  = tid - prow * 25;
    const bool is_pref = (tid < 400);

    if (is_pref) {   // x for t=0
        int tk = (int)TOK[prow * Tn + 0];
        float4 v = *(const float4*)(emb + tk * En + pc4 * 4);
        unsigned w = pk4(v.x * QS, v.y * QS, v.z * QS, v.w * QS);
        *(unsigned*)(X0 + ((prow * 128 + pc4 * 4) ^ (prow << 3))) = w;
    }
    __syncthreads();

    float hprev[4][4];
#pragma unroll
    for (int p = 0; p < 4; ++p)
#pragma unroll
        for (int j = 0; j < 4; ++j) hprev[p][j] = 0.f;

    int cur = 0;
    for (int t = 0; t < Tn; ++t) {
        const char* hc = cur ? H1 : H0;
        char*       hn = cur ? H0 : H1;
        const char* xc = cur ? X1 : X0;
        char*       xn = cur ? X0 : X1;

        float4 pref;
        const bool do_pref = is_pref && (t + 1 < Tn);
        if (do_pref) {
            int tk = (int)TOK[prow * Tn + t + 1];
            pref = *(const float4*)(emb + tk * En + pc4 * 4);
        }

        f32x4_t acc[4];
#pragma unroll
        for (int p = 0; p < 4; ++p) acc[p] = (f32x4_t){0.f, 0.f, 0.f, 0.f};

        // h @ Wh : K = 512, weights from registers
#pragma unroll
        for (int kt = 0; kt < 16; ++kt) {
            long a = *(const long*)(hc + ((r16 * 512 + kt * 32 + q * 8) ^ aswz));
#pragma unroll
            for (int p = 0; p < 4; ++p)
                acc[p] = __builtin_amdgcn_mfma_f32_16x16x32_fp8_fp8(
                    a, whf[kt][p], acc[p], 0, 0, 0);
        }
        // x @ Wx : K = 128
#pragma unroll
        for (int kt = 0; kt < 4; ++kt) {
            long a = *(const long*)(xc + ((r16 * 128 + kt * 32 + q * 8) ^ aswz));
#pragma unroll
            for (int p = 0; p < 4; ++p)
                acc[p] = __builtin_amdgcn_mfma_f32_16x16x32_fp8_fp8(
                    a, wxf[kt][p], acc[p], 0, 0, 0);
        }

        bool mk[4];
#pragma unroll
        for (int j = 0; j < 4; ++j)
            mk[j] = TOK[(rb + j) * Tn + t] != 0;

#pragma unroll
        for (int p = 0; p < 4; ++p) {
            int n = (wv * 4 + p) * 16 + r16;
#pragma unroll
            for (int j = 0; j < 4; ++j) {
                float v = acc[p][j] * INV + bias_r[p];
                v = fmaxf(v, 0.f);
                v = mk[j] ? v : hprev[p][j];
                hprev[p][j] = v;
                int row = rb + j;
                *(unsigned char*)(hn + ((row * 512 + n) ^ (row << 3))) =
                    (unsigned char)cvt1(v * QS);
            }
        }
        if (do_pref) {
            unsigned w = pk4(pref.x * QS, pref.y * QS, pref.z * QS, pref.w * QS);
            *(unsigned*)(xn + ((prow * 128 + pc4 * 4) ^ (prow << 3))) = w;
        }
        __syncthreads();
        cur ^= 1;
    }

    // final h from exact fp32 registers
#pragma unroll
    for (int p = 0; p < 4; ++p) {
        int n = (wv * 4 + p) * 16 + r16;
#pragma unroll
        for (int j = 0; j < 4; ++j)
            h_final[(r0 + rb + j) * Un + n] = hprev[p][j];
    }
}

// ---------------------------------------------------------------------------
// MLP head (unchanged — ~46 µs total, revisit if it becomes the bottleneck)
// ---------------------------------------------------------------------------
template <int K, bool RELU>
__global__ __launch_bounds__(256) void fc(
    const float* __restrict__ in, const float* __restrict__ W,
    const float* __restrict__ b, float* __restrict__ out, int N)
{
    __shared__ float in_lds[16][K];
    const int tid = threadIdx.x;
    const int r0  = blockIdx.y * 16;
    const int c0  = blockIdx.x * 32;

    for (int i = tid; i < 16 * K; i += 256) {
        int r = i / K, c = i - r * K;
        in_lds[r][c] = in[(r0 + r) * K + c];
    }
    __syncthreads();

    const int col = c0 + (tid & 31);
    const int rb  = (tid >> 5) * 2;

    float acc0 = b[col];
    float acc1 = acc0;
    const float4* i0v = (const float4*)(&in_lds[rb][0]);
    const float4* i1v = (const float4*)(&in_lds[rb + 1][0]);
    for (int k4 = 0; k4 < K / 4; ++k4) {
        float4 a = i0v[k4];
        float4 c = i1v[k4];
        int k = k4 * 4;
        float w0 = W[(k + 0) * N + col];
        float w1 = W[(k + 1) * N + col];
        float w2 = W[(k + 2) * N + col];
        float w3 = W[(k + 3) * N + col];
        acc0 += a.x * w0; acc0 += a.y * w1; acc0 += a.z * w2; acc0 += a.w * w3;
        acc1 += c.x * w0; acc1 += c.y * w1; acc1 += c.z * w2; acc1 += c.w * w3;
    }
    if (RELU) { acc0 = fmaxf(acc0, 0.f); acc1 = fmaxf(acc1, 0.f); }
    out[(r0 + rb) * N + col]     = acc0;
    out[(r0 + rb + 1) * N + col] = acc1;
}

__global__ __launch_bounds__(64) void head_softmax(
    const float* __restrict__ h2, const float* __restrict__ Wo,
    const float* __restrict__ bo, float* __restrict__ out)
{
    const int b    = blockIdx.x;
    const int lane = threadIdx.x;

    float acc[Cn];
#pragma unroll
    for (int c = 0; c < Cn; ++c) acc[c] = 0.f;

    for (int k = lane; k < D2n; k += 64) {
        float hv = h2[b * D2n + k];
#pragma unroll
        for (int c = 0; c < Cn; ++c) acc[c] += hv * Wo[k * Cn + c];
    }
#pragma unroll
    for (int c = 0; c < Cn; ++c) {
#pragma unroll
        for (int off = 32; off > 0; off >>= 1)
            acc[c] += __shfl_down(acc[c], off);
    }
    if (lane == 0) {
        float l[Cn], mx = -1e30f;
#pragma unroll
        for (int c = 0; c < Cn; ++c) { l[c] = acc[c] + bo[c]; mx = fmaxf(mx, l[c]); }
        float s = 0.f;
#pragma unroll
        for (int c = 0; c < Cn; ++c) { l[c] = __expf(l[c] - mx); s += l[c]; }
        float inv = 1.f / s;
#pragma unroll
        for (int c = 0; c < Cn; ++c) out[b * Cn + c] = l[c] * inv;
    }
}

extern "C" void kernel_launch(void* const* d_in, const int* in_sizes, int n_in,
                              void* d_out, int out_size, void* d_ws, size_t ws_size,
                              hipStream_t stream)
{
    const int*   tokens = (const int*)d_in[0];
    const float* emb    = (const float*)d_in[1];
    const float* Wx     = (const float*)d_in[2];
    const float* Wh     = (const float*)d_in[3];
    const float* b_rnn  = (const float*)d_in[4];
    const float* W1     = (const float*)d_in[5];
    const float* b1     = (const float*)d_in[6];
    const float* W2     = (const float*)d_in[7];
    const float* b2     = (const float*)d_in[8];
    const float* Wo     = (const float*)d_in[9];
    const float* bo     = (const float*)d_in[10];
    float* out = (float*)d_out;

    char* ws = (char*)d_ws;
    unsigned char* WhP8 = (unsigned char*)ws;                 // 256 KB
    unsigned char* WxP8 = (unsigned char*)(ws + (256 << 10)); // 64 KB
    float* h_last = (float*)(ws + (320 << 10));               // 512 KB
    float* h1     = (float*)(ws + (832 << 10));               // 1 MB
    float* h2     = (float*)(ws + (1856 << 10));              // 1 MB

    pack_wh8<<<1024, 256, 0, stream>>>(Wh, WhP8);
    pack_wx8<<<256, 256, 0, stream>>>(Wx, WxP8);

    rnn_persist8<<<Bn / 16, 512, 0, stream>>>(
        tokens, emb, b_rnn, (const long*)WhP8, (const long*)WxP8, h_last);

    dim3 bs(256);
    fc<Un, true><<<dim3(D1n / 32, Bn / 16), bs, 0, stream>>>(h_last, W1, b1, h1, D1n);
    fc<D1n, true><<<dim3(D2n / 32, Bn / 16), bs, 0, stream>>>(h1, W2, b2, h2, D2n);
    head_softmax<<<Bn, 64, 0, stream>>>(h2, Wo, bo, out);
}